// Round 8
// baseline (325.345 us; speedup 1.0000x reference)
//
#include <hip/hip_runtime.h>

#define SDIM 4096
#define HDIM 256
#define WIN 128
#define NROW 16384
#define QSCALE 0.0625f  // 1/sqrt(256)
#define NBLK 512u

typedef __attribute__((ext_vector_type(8))) short bf16x8;
typedef __attribute__((ext_vector_type(4))) float f32x4;

static __device__ __forceinline__ unsigned short f2bf(float f) {
  unsigned int u = __float_as_uint(f);
  return (unsigned short)((u + 0x7fffu + ((u >> 16) & 1u)) >> 16);
}

#define MFMA16(a, b, c) __builtin_amdgcn_mfma_f32_16x16x32_bf16((a), (b), (c), 0, 0, 0)

// Frag-packed layout (per 16-row tile, per kk): pack[tile][kk][lane][j] =
//   M[16*tile + (lane&15)][32*kk + 8*(lane>>4) + j]  -> wave load = base+lane*8.
// V PV-packed: Vp[tile][dt][gg][l15][j] = V[16*tile + 8*gg + j][16*dt + l15].

union SharedU {
  unsigned short st[32][264];  // phase B stage (16.9 KB)
  struct {                     // phase C (43.8 KB total union)
    float obuf[2][16][260];
    float lbuf[2][16];
    float linv[32];
    unsigned short plds[4][2][16][40];
  } c;
};

// Spin grid-barrier: one-shot per slot (no generation reuse), device scope.
__device__ __forceinline__ void grid_barrier(unsigned* bar, int slot) {
  __syncthreads();
  if (threadIdx.x == 0) {
    unsigned* cnt = bar + slot * 16;      // separate cachelines per slot
    unsigned* gen = bar + slot * 16 + 8;
    __threadfence();  // release prior writes (device scope)
    unsigned arrived = __hip_atomic_fetch_add(cnt, 1u, __ATOMIC_ACQ_REL,
                                              __HIP_MEMORY_SCOPE_AGENT);
    if (arrived == NBLK - 1) {
      __hip_atomic_store(gen, 1u, __ATOMIC_RELEASE, __HIP_MEMORY_SCOPE_AGENT);
    } else {
      while (__hip_atomic_load(gen, __ATOMIC_ACQUIRE,
                               __HIP_MEMORY_SCOPE_AGENT) == 0u)
        __builtin_amdgcn_s_sleep(2);
    }
    __threadfence();  // acquire side for subsequent plain loads
  }
  __syncthreads();
}

__global__ __launch_bounds__(256, 3) void mega(
    const float* __restrict__ x,
    const float* __restrict__ Wq, const float* __restrict__ bq,
    const float* __restrict__ Wk, const float* __restrict__ bk,
    const float* __restrict__ Wv, const float* __restrict__ bv,
    unsigned short* __restrict__ Wp, unsigned short* __restrict__ Qp,
    unsigned short* __restrict__ Kp, unsigned short* __restrict__ Vp,
    float* __restrict__ partial, float* __restrict__ p2,
    float* __restrict__ out, unsigned* bar) {
  __shared__ SharedU sh;
  const int b = blockIdx.x;
  const int tid = threadIdx.x;
  const int lane = tid & 63, w = tid >> 6;
  const int l15 = lane & 15, g = lane >> 4;

  // ---------------- Phase A: W -> frag-packed bf16 (192 blocks) ----------
  if (b < 192) {
    const int m = b >> 6, nt = (b >> 2) & 15, kkp = b & 3;
    const float* __restrict__ W = (m == 0) ? Wq : (m == 1) ? Wk : Wv;
    const int l2 = tid & 63, jh = tid >> 6;
    const int g2 = l2 >> 4, c2 = l2 & 15;
#pragma unroll
    for (int kh = 0; kh < 2; ++kh) {
      int kk = kkp * 2 + kh;
      float v0 = W[(size_t)(32 * kk + 8 * g2 + 2 * jh) * HDIM + 16 * nt + c2];
      float v1 = W[(size_t)(32 * kk + 8 * g2 + 2 * jh + 1) * HDIM + 16 * nt + c2];
      unsigned int pk = (unsigned int)f2bf(v0) | ((unsigned int)f2bf(v1) << 16);
      *(unsigned int*)(Wp + ((size_t)(m * 16 + nt) * 8 + kk) * 512 +
                       (size_t)l2 * 8 + 2 * jh) = pk;
    }
  }
  grid_barrier(bar, 0);

  // ---------------- Phase B: QKV projection (512 blocks x 32 rows) -------
  {
    const size_t rb = (size_t)b * 32;
#pragma unroll
    for (int it = 0; it < 8; ++it) {
      int u = it * 256 + tid;  // float4 index over 32x256
      int r = u >> 6, c4 = (u & 63) << 2;
      float4 f = *(const float4*)(x + (rb + r) * HDIM + c4);
      sh.st[r][c4 + 0] = f2bf(f.x);
      sh.st[r][c4 + 1] = f2bf(f.y);
      sh.st[r][c4 + 2] = f2bf(f.z);
      sh.st[r][c4 + 3] = f2bf(f.w);
    }
    __syncthreads();
    const int rtl = w >> 1, nh = w & 1;  // wave = (row-tile, nt-half)
    bf16x8 a[8];
#pragma unroll
    for (int kk = 0; kk < 8; ++kk)
      a[kk] = *(const bf16x8*)&sh.st[16 * rtl + l15][32 * kk + 8 * g];
    __syncthreads();  // x-stage consumed; st becomes out-stage
    const int tg0 = b * 2;
    for (int m = 0; m < 3; ++m) {
      const unsigned short* Wm = Wp + (size_t)m * 65536;
      const float* bias = (m == 0) ? bq : (m == 1) ? bk : bv;
#pragma unroll 2
      for (int ntp = 0; ntp < 4; ++ntp) {
        int nt0 = nh * 8 + ntp * 2;
        const unsigned short* w0p = Wm + (size_t)nt0 * 4096 + (size_t)lane * 8;
        const unsigned short* w1p = w0p + 4096;
        f32x4 a0 = {0.f, 0.f, 0.f, 0.f}, a1 = {0.f, 0.f, 0.f, 0.f};
#pragma unroll
        for (int kk = 0; kk < 8; ++kk) {
          a0 = MFMA16(a[kk], *(const bf16x8*)(w0p + kk * 512), a0);
          a1 = MFMA16(a[kk], *(const bf16x8*)(w1p + kk * 512), a1);
        }
        float b0 = bias[nt0 * 16 + l15], b1 = bias[nt0 * 16 + 16 + l15];
#pragma unroll
        for (int r = 0; r < 4; ++r) {
          sh.st[16 * rtl + 4 * g + r][nt0 * 16 + l15] = f2bf(a0[r] + b0);
          sh.st[16 * rtl + 4 * g + r][nt0 * 16 + 16 + l15] = f2bf(a1[r] + b1);
        }
      }
      __syncthreads();
      if (m < 2) {
        unsigned short* O = (m == 0 ? Qp : Kp);
#pragma unroll
        for (int it = 0; it < 4; ++it) {
          int u = it * 256 + tid;
          int ln = u & 63, kk = (u >> 6) & 7, tgl = u >> 9;
          int lg = ln >> 4, lc = ln & 15;
          bf16x8 vv = *(const bf16x8*)&sh.st[16 * tgl + lc][32 * kk + 8 * lg];
          *(bf16x8*)(O + ((size_t)(tg0 + tgl) * 8 + kk) * 512 + (size_t)ln * 8) = vv;
        }
      } else {
#pragma unroll
        for (int it = 0; it < 4; ++it) {
          int u = it * 256 + tid;
          int lc = u & 15, gg = (u >> 4) & 1, dt = (u >> 5) & 15, tgl = u >> 9;
          bf16x8 vv;
#pragma unroll
          for (int j = 0; j < 8; ++j)
            vv[j] = (short)sh.st[16 * tgl + 8 * gg + j][16 * dt + lc];
          *(bf16x8*)(Vp + (size_t)(tg0 + tgl) * 4096 +
                     (size_t)(dt * 32 + gg * 16 + lc) * 8) = vv;
        }
      }
      __syncthreads();
    }
  }
  grid_barrier(bar, 1);

  // ---------------- Phase C: banded attention (2 q-tiles per block) ------
  {
    const int tA = (b & 7) * 128 + (b >> 3);  // XCD-local contiguous q-range
    const int tile = (w & 2) ? tA + 64 : tA;
    const int half = w & 1;  // chunk half {0..4} / {5..8}
    const int batch = tile >> 8, qt = tile & 255, s0 = qt << 4;
    const int tbase = batch << 8;
    bf16x8 qf[8];
    const unsigned short* qp_ = Qp + (size_t)tile * 4096 + (size_t)lane * 8;
#pragma unroll
    for (int kk = 0; kk < 8; ++kk) qf[kk] = *(const bf16x8*)(qp_ + kk * 512);
    f32x4 acc[16];
    const f32x4 zero = {0.f, 0.f, 0.f, 0.f};
#pragma unroll
    for (int i = 0; i < 16; ++i) acc[i] = zero;
    float lacc[4] = {0.f, 0.f, 0.f, 0.f};
    for (int c = half ? 5 : 0; c < (half ? 9 : 5); ++c) {
      const int t0 = s0 - WIN + c * 32;
      if (t0 + 32 <= 0 || t0 >= SDIM) continue;  // wave-uniform skip
      const int tgloc = t0 >> 4;
      const int tga = tbase + min(max(tgloc, 0), 255);
      const int tgb = tbase + min(max(tgloc + 1, 0), 255);
      const unsigned short* kap = Kp + (size_t)tga * 4096 + (size_t)lane * 8;
      const unsigned short* kbp = Kp + (size_t)tgb * 4096 + (size_t)lane * 8;
      f32x4 sA_ = zero, sB_ = zero;
#pragma unroll
      for (int kk = 0; kk < 8; ++kk) {
        sA_ = MFMA16(qf[kk], *(const bf16x8*)(kap + kk * 512), sA_);
        sB_ = MFMA16(qf[kk], *(const bf16x8*)(kbp + kk * 512), sB_);
      }
      float p0[4], p1[4];
#pragma unroll
      for (int r = 0; r < 4; ++r) {
        int s = s0 + 4 * g + r;
        int ta = t0 + l15, tb = t0 + 16 + l15;
        bool okA = (ta >= 0) && (ta < SDIM) && (ta - s <= WIN) && (ta - s >= -WIN);
        bool okB = (tb >= 0) && (tb < SDIM) && (tb - s <= WIN) && (tb - s >= -WIN);
        p0[r] = okA ? __expf(sA_[r] * QSCALE) : 0.f;
        p1[r] = okB ? __expf(sB_[r] * QSCALE) : 0.f;
      }
#pragma unroll
      for (int r = 0; r < 4; ++r) {
        float v = p0[r] + p1[r];
        v += __shfl_xor(v, 1);
        v += __shfl_xor(v, 2);
        v += __shfl_xor(v, 4);
        v += __shfl_xor(v, 8);
        lacc[r] += v;
      }
      const int bsel = c & 1;
#pragma unroll
      for (int r = 0; r < 4; ++r) {
        sh.c.plds[w][bsel][4 * g + r][l15] = f2bf(p0[r]);
        sh.c.plds[w][bsel][4 * g + r][16 + l15] = f2bf(p1[r]);
      }
      bf16x8 pa = *(const bf16x8*)&sh.c.plds[w][bsel][l15][8 * g];
      const int tgv = tbase + min(max(tgloc + (g >> 1), 0), 255);
      const unsigned short* vp_ = Vp + (size_t)tgv * 4096 +
                                  (size_t)(g & 1) * 128 + (size_t)l15 * 8;
#pragma unroll
      for (int dt = 0; dt < 16; ++dt)
        acc[dt] = MFMA16(pa, *(const bf16x8*)(vp_ + dt * 256), acc[dt]);
    }
    // 2-way parallel combine per tile (waves 0/1 -> obuf[0], 2/3 -> obuf[1])
    const int ob = w >> 1;
    if (!(w & 1)) {
#pragma unroll
      for (int dt = 0; dt < 16; ++dt)
#pragma unroll
        for (int r = 0; r < 4; ++r)
          sh.c.obuf[ob][4 * g + r][dt * 16 + l15] = acc[dt][r];
      if (l15 == 0)
#pragma unroll
        for (int r = 0; r < 4; ++r) sh.c.lbuf[ob][4 * g + r] = lacc[r];
    }
    __syncthreads();
    if (w & 1) {
#pragma unroll
      for (int dt = 0; dt < 16; ++dt)
#pragma unroll
        for (int r = 0; r < 4; ++r)
          sh.c.obuf[ob][4 * g + r][dt * 16 + l15] += acc[dt][r];
      if (l15 == 0)
#pragma unroll
        for (int r = 0; r < 4; ++r) sh.c.lbuf[ob][4 * g + r] += lacc[r];
    }
    __syncthreads();
    if (tid < 32) sh.c.linv[tid] = 1.0f / sh.c.lbuf[tid >> 4][tid & 15];
    __syncthreads();
    float sA = 0.f, sB = 0.f;
#pragma unroll
    for (int row = 0; row < 16; ++row) {
      sA += sh.c.obuf[0][row][tid] * sh.c.linv[row];
      sB += sh.c.obuf[1][row][tid] * sh.c.linv[16 + row];
    }
    partial[(size_t)tA * HDIM + tid] = sA;
    partial[(size_t)(tA + 64) * HDIM + tid] = sB;
  }
  grid_barrier(bar, 2);

  // ---------------- Phase D: deterministic mean over S --------------------
  if (b < 256) {
    const int bb = b >> 6, seg = b & 63;
    float s = 0.f;
#pragma unroll
    for (int i = 0; i < 4; ++i)
      s += partial[((size_t)bb * 256 + seg * 4 + i) * HDIM + tid];
    p2[(size_t)b * HDIM + tid] = s;
  }
  grid_barrier(bar, 3);
  if (b < 4) {
    float s = 0.f;
#pragma unroll 8
    for (int i = 0; i < 64; ++i) s += p2[((size_t)b * 64 + i) * HDIM + tid];
    out[(size_t)b * HDIM + tid] = s * (1.0f / (float)SDIM);
  }
}

extern "C" void kernel_launch(void* const* d_in, const int* in_sizes, int n_in,
                              void* d_out, int out_size, void* d_ws, size_t ws_size,
                              hipStream_t stream) {
  const float* x  = (const float*)d_in[0];
  const float* Wq = (const float*)d_in[1];
  const float* bq = (const float*)d_in[2];
  const float* Wk = (const float*)d_in[3];
  const float* bk = (const float*)d_in[4];
  const float* Wv = (const float*)d_in[5];
  const float* bv = (const float*)d_in[6];
  float* out = (float*)d_out;

  unsigned short* Wp = (unsigned short*)d_ws;           // 384 KB
  unsigned short* Qp = Wp + 3 * 65536;                  // 8.4 MB
  unsigned short* Kp = Qp + (size_t)NROW * HDIM;        // 8.4 MB
  unsigned short* Vp = Kp + (size_t)NROW * HDIM;        // 8.4 MB
  float* partial = (float*)(Vp + (size_t)NROW * HDIM);  // 1 MB
  float* p2 = partial + (size_t)1024 * HDIM;            // 256 KB
  unsigned* bar = (unsigned*)(p2 + (size_t)256 * HDIM); // 256 B

  hipMemsetAsync(bar, 0, 4 * 16 * sizeof(unsigned), stream);
  mega<<<NBLK, 256, 0, stream>>>(x, Wq, bq, Wk, bk, Wv, bv, Wp, Qp, Kp, Vp,
                                 partial, p2, out, bar);
}

// Round 9
// 68.993 us; speedup vs baseline: 4.7156x; 4.7156x over previous
//
#include <hip/hip_runtime.h>

#define SDIM 4096
#define HDIM 256
#define WIN 128
#define NROW 16384  // B*S
#define QSCALE 0.0625f  // 1/sqrt(256)

typedef __attribute__((ext_vector_type(8))) short bf16x8;
typedef __attribute__((ext_vector_type(4))) float f32x4;

static __device__ __forceinline__ unsigned short f2bf(float f) {
  unsigned int u = __float_as_uint(f);
  return (unsigned short)((u + 0x7fffu + ((u >> 16) & 1u)) >> 16);
}

#define MFMA16(a, b, c) __builtin_amdgcn_mfma_f32_16x16x32_bf16((a), (b), (c), 0, 0, 0)

// Frag-packed layout (per 16-row tile, per kk): pack[tile][kk][lane][j] =
//   M[16*tile + (lane&15)][32*kk + 8*(lane>>4) + j]  -> wave load = base+lane*8.
// V PV-packed: Vp[tile][dt][gg][l15][j] = V[16*tile + 8*gg + j][16*dt + l15].

// ---------- Kernel 0: W -> frag-packed bf16 W^T ----------
__global__ __launch_bounds__(256) void wconv(const float* __restrict__ Wq,
                                             const float* __restrict__ Wk,
                                             const float* __restrict__ Wv,
                                             unsigned short* __restrict__ Wp) {
  const int m = blockIdx.y, nt = blockIdx.x;
  const float* __restrict__ W = (m == 0) ? Wq : (m == 1) ? Wk : Wv;
  const int tid = threadIdx.x, lane = tid & 63, w = tid >> 6;
  const int l15 = lane & 15, g = lane >> 4;
#pragma unroll
  for (int half = 0; half < 2; ++half) {
    int kk = w * 2 + half;
    bf16x8 v;
#pragma unroll
    for (int j = 0; j < 8; ++j)
      v[j] = (short)f2bf(W[(size_t)(32 * kk + 8 * g + j) * HDIM + 16 * nt + l15]);
    *(bf16x8*)(Wp + ((size_t)(m * 16 + nt) * 8 + kk) * 512 + (size_t)lane * 8) = v;
  }
}

// ---------- Kernel 1: QKV projection; m-loop inside, 16 rows/block ----------
// grid 1024, block 256 (4 waves; wave w owns nt range [4w, 4w+4) for all 3 m).
__global__ __launch_bounds__(256) void qkv_mfma(
    const float* __restrict__ x, const unsigned short* __restrict__ Wp,
    const float* __restrict__ bq, const float* __restrict__ bk,
    const float* __restrict__ bv, unsigned short* __restrict__ Qp,
    unsigned short* __restrict__ Kp, unsigned short* __restrict__ Vp) {
  __shared__ unsigned short st[16][264];  // x-stage, then out-stage (8.4 KB)
  const int tid = threadIdx.x;
  const int lane = tid & 63, w = tid >> 6;
  const int l15 = lane & 15, g = lane >> 4;
  const int tg = blockIdx.x;  // 16-row tile index, 0..1023
  const size_t rb = (size_t)tg * 16;
  // ---- stage 16 rows of x, coalesced fp32 read, bf16 convert ----
#pragma unroll
  for (int it = 0; it < 4; ++it) {
    int u = it * 256 + tid;  // float4 index over 16x256
    int r = u >> 6, c4 = (u & 63) << 2;
    float4 f = *(const float4*)(x + (rb + r) * HDIM + c4);
    st[r][c4 + 0] = f2bf(f.x);
    st[r][c4 + 1] = f2bf(f.y);
    st[r][c4 + 2] = f2bf(f.z);
    st[r][c4 + 3] = f2bf(f.w);
  }
  __syncthreads();
  bf16x8 a[8];  // A-frags held in registers for the whole kernel
#pragma unroll
  for (int kk = 0; kk < 8; ++kk)
    a[kk] = *(const bf16x8*)&st[l15][32 * kk + 8 * g];
  __syncthreads();  // x-stage consumed; st becomes out-stage
  for (int m = 0; m < 3; ++m) {
    const unsigned short* Wm = Wp + (size_t)m * 65536;
    const float* bias = (m == 0) ? bq : (m == 1) ? bk : bv;
#pragma unroll
    for (int p = 0; p < 2; ++p) {
      int nt0 = 4 * w + 2 * p;
      const unsigned short* w0p = Wm + (size_t)nt0 * 4096 + (size_t)lane * 8;
      const unsigned short* w1p = w0p + 4096;
      f32x4 a0 = {0.f, 0.f, 0.f, 0.f}, a1 = {0.f, 0.f, 0.f, 0.f};
#pragma unroll
      for (int kk = 0; kk < 8; ++kk) {
        a0 = MFMA16(a[kk], *(const bf16x8*)(w0p + kk * 512), a0);
        a1 = MFMA16(a[kk], *(const bf16x8*)(w1p + kk * 512), a1);
      }
      float b0 = bias[nt0 * 16 + l15], b1 = bias[nt0 * 16 + 16 + l15];
#pragma unroll
      for (int r = 0; r < 4; ++r) {
        st[4 * g + r][nt0 * 16 + l15] = f2bf(a0[r] + b0);
        st[4 * g + r][nt0 * 16 + 16 + l15] = f2bf(a1[r] + b1);
      }
    }
    __syncthreads();
    if (m < 2) {
      unsigned short* O = (m == 0 ? Qp : Kp) + (size_t)tg * 4096;
#pragma unroll
      for (int it = 0; it < 2; ++it) {
        int u = it * 256 + tid;  // u < 512: (kk, lane)
        int ln = u & 63, kk = u >> 6;
        int lg = ln >> 4, lc = ln & 15;
        bf16x8 vv = *(const bf16x8*)&st[lc][32 * kk + 8 * lg];
        *(bf16x8*)(O + (size_t)kk * 512 + (size_t)ln * 8) = vv;
      }
    } else {
      unsigned short* O = Vp + (size_t)tg * 4096;
#pragma unroll
      for (int it = 0; it < 2; ++it) {
        int u = it * 256 + tid;  // u < 512: [dt][gg][lc]
        int lc = u & 15, gg = (u >> 4) & 1, dt = u >> 5;
        bf16x8 vv;
#pragma unroll
        for (int j = 0; j < 8; ++j)
          vv[j] = (short)st[8 * gg + j][16 * dt + lc];
        *(bf16x8*)(O + (size_t)u * 8) = vv;
      }
    }
    __syncthreads();  // out-stage drained before next m overwrites
  }
}

// ---------- Kernel 2: banded attention, all-MFMA, coalesced packed loads ----------
// grid 1024 (XCD-swizzled), block 256 = 4 waves; chunks {3,2,2,2} split by wave.
__global__ __launch_bounds__(256) void attn_mfma(
    const unsigned short* __restrict__ Qp, const unsigned short* __restrict__ Kp,
    const unsigned short* __restrict__ Vp, float* __restrict__ partial) {
  __shared__ float obuf[16][260];
  __shared__ float lbuf[16];
  __shared__ float linv[16];
  __shared__ unsigned short plds[4][2][16][40];
  const int tid = threadIdx.x;
  const int lane = tid & 63, w = tid >> 6;
  const int bid = blockIdx.x;
  const int blk = (bid & 7) * 128 + (bid >> 3);  // bijective XCD swizzle
  const int b = blk >> 8;
  const int qt = blk & 255;
  const int s0 = qt << 4;
  const int l15 = lane & 15, g = lane >> 4;
  bf16x8 qf[8];
  const unsigned short* qp_ = Qp + ((size_t)b * 256 + qt) * 4096 + (size_t)lane * 8;
#pragma unroll
  for (int kk = 0; kk < 8; ++kk) qf[kk] = *(const bf16x8*)(qp_ + kk * 512);
  const unsigned short* Kb = Kp + (size_t)b * 1048576;
  const unsigned short* Vb = Vp + (size_t)b * 1048576;
  f32x4 acc[16];
  const f32x4 zero = {0.f, 0.f, 0.f, 0.f};
#pragma unroll
  for (int i = 0; i < 16; ++i) acc[i] = zero;
  float lacc[4] = {0.f, 0.f, 0.f, 0.f};
  const int cb = (w == 0) ? 0 : 1 + 2 * w;  // {0,3,5,7}
  const int ce = 3 + 2 * w;                 // {3,5,7,9}
  for (int c = cb; c < ce; ++c) {
    const int t0 = s0 - WIN + c * 32;
    if (t0 + 32 <= 0 || t0 >= SDIM) continue;  // wave-uniform skip
    const int tg = t0 >> 4;
    const int tga = min(max(tg, 0), 255);
    const int tgb = min(max(tg + 1, 0), 255);
    const unsigned short* kap = Kb + (size_t)tga * 4096 + (size_t)lane * 8;
    const unsigned short* kbp = Kb + (size_t)tgb * 4096 + (size_t)lane * 8;
    f32x4 sA = zero, sB = zero;
#pragma unroll
    for (int kk = 0; kk < 8; ++kk) {
      sA = MFMA16(qf[kk], *(const bf16x8*)(kap + kk * 512), sA);
      sB = MFMA16(qf[kk], *(const bf16x8*)(kbp + kk * 512), sB);
    }
    float p0[4], p1[4];
#pragma unroll
    for (int r = 0; r < 4; ++r) {
      int s = s0 + 4 * g + r;
      int ta = t0 + l15, tb = t0 + 16 + l15;
      bool okA = (ta >= 0) && (ta < SDIM) && (ta - s <= WIN) && (ta - s >= -WIN);
      bool okB = (tb >= 0) && (tb < SDIM) && (tb - s <= WIN) && (tb - s >= -WIN);
      p0[r] = okA ? __expf(sA[r] * QSCALE) : 0.f;
      p1[r] = okB ? __expf(sB[r] * QSCALE) : 0.f;
    }
#pragma unroll
    for (int r = 0; r < 4; ++r) {
      float v = p0[r] + p1[r];
      v += __shfl_xor(v, 1);
      v += __shfl_xor(v, 2);
      v += __shfl_xor(v, 4);
      v += __shfl_xor(v, 8);
      lacc[r] += v;
    }
    const int bsel = c & 1;
#pragma unroll
    for (int r = 0; r < 4; ++r) {
      plds[w][bsel][4 * g + r][l15] = f2bf(p0[r]);
      plds[w][bsel][4 * g + r][16 + l15] = f2bf(p1[r]);
    }
    bf16x8 pa = *(const bf16x8*)&plds[w][bsel][l15][8 * g];
    const int tgv = min(max(tg + (g >> 1), 0), 255);
    const unsigned short* vp_ =
        Vb + (size_t)tgv * 4096 + (size_t)(g & 1) * 128 + (size_t)l15 * 8;
#pragma unroll
    for (int dt = 0; dt < 16; ++dt)
      acc[dt] = MFMA16(pa, *(const bf16x8*)(vp_ + dt * 256), acc[dt]);
  }
  // ---- combine the 4 waves' (O,l) partials in LDS ----
  if (w == 0) {
#pragma unroll
    for (int dt = 0; dt < 16; ++dt)
#pragma unroll
      for (int r = 0; r < 4; ++r) obuf[4 * g + r][dt * 16 + l15] = acc[dt][r];
    if (l15 == 0)
#pragma unroll
      for (int r = 0; r < 4; ++r) lbuf[4 * g + r] = lacc[r];
  }
  __syncthreads();
#pragma unroll
  for (int wv = 1; wv < 4; ++wv) {
    if (w == wv) {
#pragma unroll
      for (int dt = 0; dt < 16; ++dt)
#pragma unroll
        for (int r = 0; r < 4; ++r) obuf[4 * g + r][dt * 16 + l15] += acc[dt][r];
      if (l15 == 0)
#pragma unroll
        for (int r = 0; r < 4; ++r) lbuf[4 * g + r] += lacc[r];
    }
    __syncthreads();
  }
  if (tid < 16) linv[tid] = 1.0f / lbuf[tid];
  __syncthreads();
  float s = 0.f;
#pragma unroll
  for (int row = 0; row < 16; ++row) s += obuf[row][tid] * linv[row];
  partial[(size_t)blk * HDIM + tid] = s;
}

// ---------- Kernel 3: deterministic mean over S (64 blocks) ----------
__global__ __launch_bounds__(256) void reduce_partials(
    const float* __restrict__ partial, float* __restrict__ out) {
  __shared__ float red[16][17];
  const int cx = blockIdx.x, b = blockIdx.y;
  const int lc = threadIdx.x & 15, rg = threadIdx.x >> 4;
  float s = 0.f;
#pragma unroll
  for (int i = 0; i < 16; ++i)
    s += partial[((size_t)b * 256 + rg * 16 + i) * HDIM + cx * 16 + lc];
  red[rg][lc] = s;
  __syncthreads();
  if (rg == 0) {
    float t = 0.f;
#pragma unroll
    for (int r = 0; r < 16; ++r) t += red[r][lc];
    out[(size_t)b * HDIM + cx * 16 + lc] = t * (1.0f / (float)SDIM);
  }
}

extern "C" void kernel_launch(void* const* d_in, const int* in_sizes, int n_in,
                              void* d_out, int out_size, void* d_ws, size_t ws_size,
                              hipStream_t stream) {
  const float* x  = (const float*)d_in[0];
  const float* Wq = (const float*)d_in[1];
  const float* bq = (const float*)d_in[2];
  const float* Wk = (const float*)d_in[3];
  const float* bk = (const float*)d_in[4];
  const float* Wv = (const float*)d_in[5];
  const float* bv = (const float*)d_in[6];
  float* out = (float*)d_out;

  unsigned short* Wp = (unsigned short*)d_ws;           // 384 KB
  unsigned short* Qp = Wp + 3 * 65536;                  // 8.4 MB
  unsigned short* Kp = Qp + (size_t)NROW * HDIM;        // 8.4 MB
  unsigned short* Vp = Kp + (size_t)NROW * HDIM;        // 8.4 MB
  float* partial = (float*)(Vp + (size_t)NROW * HDIM);  // 1 MB

  dim3 wg(16, 3);
  wconv<<<wg, 256, 0, stream>>>(Wq, Wk, Wv, Wp);
  qkv_mfma<<<1024, 256, 0, stream>>>(x, Wp, bq, bk, bv, Qp, Kp, Vp);
  attn_mfma<<<1024, 256, 0, stream>>>(Qp, Kp, Vp, partial);
  dim3 rg(16, 4);
  reduce_partials<<<rg, 256, 0, stream>>>(partial, out);
}

// Round 10
// 51.759 us; speedup vs baseline: 6.2858x; 1.3330x over previous
//
#include <hip/hip_runtime.h>

#define SDIM 4096
#define HDIM 256
#define WIN 128
#define NROW 16384  // B*S
#define QSCALE 0.0625f  // 1/sqrt(256)

typedef __attribute__((ext_vector_type(8))) short bf16x8;
typedef __attribute__((ext_vector_type(4))) float f32x4;

static __device__ __forceinline__ unsigned short f2bf(float f) {
  unsigned int u = __float_as_uint(f);
  return (unsigned short)((u + 0x7fffu + ((u >> 16) & 1u)) >> 16);
}

#define MFMA16(a, b, c) __builtin_amdgcn_mfma_f32_16x16x32_bf16((a), (b), (c), 0, 0, 0)

// Frag-packed layout (per 16-row tile, per kk): pack[tile][kk][lane][j] =
//   M[16*tile + (lane&15)][32*kk + 8*(lane>>4) + j]  -> wave load = base+lane*8.
// V PV-packed: Vp[tile][dt][gg][l15][j] = V[16*tile + 8*gg + j][16*dt + l15].

// ---------- Kernel 0: W -> frag-packed bf16 W^T ----------
__global__ __launch_bounds__(256) void wconv(const float* __restrict__ Wq,
                                             const float* __restrict__ Wk,
                                             const float* __restrict__ Wv,
                                             unsigned short* __restrict__ Wp) {
  const int m = blockIdx.y, nt = blockIdx.x;
  const float* __restrict__ W = (m == 0) ? Wq : (m == 1) ? Wk : Wv;
  const int tid = threadIdx.x, lane = tid & 63, w = tid >> 6;
  const int l15 = lane & 15, g = lane >> 4;
#pragma unroll
  for (int half = 0; half < 2; ++half) {
    int kk = w * 2 + half;
    bf16x8 v;
#pragma unroll
    for (int j = 0; j < 8; ++j)
      v[j] = (short)f2bf(W[(size_t)(32 * kk + 8 * g + j) * HDIM + 16 * nt + l15]);
    *(bf16x8*)(Wp + ((size_t)(m * 16 + nt) * 8 + kk) * 512 + (size_t)lane * 8) = v;
  }
}

// ---------- Kernel 1: QKV; 32 rows/block, wave = nt-quarter x 2 row-tiles ----
// grid 512, block 256. Each W-frag load feeds 16 MFMA (2 row-tiles).
__global__ __launch_bounds__(256) void qkv_mfma(
    const float* __restrict__ x, const unsigned short* __restrict__ Wp,
    const float* __restrict__ bq, const float* __restrict__ bk,
    const float* __restrict__ bv, unsigned short* __restrict__ Qp,
    unsigned short* __restrict__ Kp, unsigned short* __restrict__ Vp) {
  __shared__ unsigned short st[32][264];  // x-stage, then out-stage (16.9 KB)
  const int tid = threadIdx.x;
  const int lane = tid & 63, w = tid >> 6;
  const int l15 = lane & 15, g = lane >> 4;
  const size_t rb = (size_t)blockIdx.x * 32;
  // ---- stage 32 rows of x, coalesced fp32 read, bf16 convert ----
#pragma unroll
  for (int it = 0; it < 8; ++it) {
    int u = it * 256 + tid;  // float4 index over 32x256
    int r = u >> 6, c4 = (u & 63) << 2;
    float4 f = *(const float4*)(x + (rb + r) * HDIM + c4);
    st[r][c4 + 0] = f2bf(f.x);
    st[r][c4 + 1] = f2bf(f.y);
    st[r][c4 + 2] = f2bf(f.z);
    st[r][c4 + 3] = f2bf(f.w);
  }
  __syncthreads();
  bf16x8 a[2][8];  // A-frags for both row-tiles, held all kernel
#pragma unroll
  for (int rtl = 0; rtl < 2; ++rtl)
#pragma unroll
    for (int kk = 0; kk < 8; ++kk)
      a[rtl][kk] = *(const bf16x8*)&st[16 * rtl + l15][32 * kk + 8 * g];
  __syncthreads();  // x-stage consumed; st becomes out-stage
  const int tg0 = blockIdx.x * 2;
  for (int m = 0; m < 3; ++m) {
    const unsigned short* Wm = Wp + (size_t)m * 65536;
    const float* bias = (m == 0) ? bq : (m == 1) ? bk : bv;
#pragma unroll
    for (int ntl = 0; ntl < 4; ++ntl) {
      const int nt = 4 * w + ntl;
      const unsigned short* wp_ = Wm + (size_t)nt * 4096 + (size_t)lane * 8;
      bf16x8 wf[8];
#pragma unroll
      for (int kk = 0; kk < 8; ++kk) wf[kk] = *(const bf16x8*)(wp_ + kk * 512);
      f32x4 a0 = {0.f, 0.f, 0.f, 0.f}, a1 = {0.f, 0.f, 0.f, 0.f};
#pragma unroll
      for (int kk = 0; kk < 8; ++kk) {
        a0 = MFMA16(a[0][kk], wf[kk], a0);
        a1 = MFMA16(a[1][kk], wf[kk], a1);
      }
      float bn = bias[nt * 16 + l15];
#pragma unroll
      for (int r = 0; r < 4; ++r) {
        st[4 * g + r][nt * 16 + l15] = f2bf(a0[r] + bn);
        st[16 + 4 * g + r][nt * 16 + l15] = f2bf(a1[r] + bn);
      }
    }
    __syncthreads();
    if (m < 2) {
      unsigned short* O = (m == 0 ? Qp : Kp);
#pragma unroll
      for (int it = 0; it < 4; ++it) {
        int u = it * 256 + tid;  // (tgl, kk, lane)
        int ln = u & 63, kk = (u >> 6) & 7, tgl = u >> 9;
        int lg = ln >> 4, lc = ln & 15;
        bf16x8 vv = *(const bf16x8*)&st[16 * tgl + lc][32 * kk + 8 * lg];
        *(bf16x8*)(O + ((size_t)(tg0 + tgl) * 8 + kk) * 512 + (size_t)ln * 8) = vv;
      }
    } else {
#pragma unroll
      for (int it = 0; it < 4; ++it) {
        int u = it * 256 + tid;  // [tgl][dt][gg][lc]
        int lc = u & 15, gg = (u >> 4) & 1, dt = (u >> 5) & 15, tgl = u >> 9;
        bf16x8 vv;
#pragma unroll
        for (int j = 0; j < 8; ++j)
          vv[j] = (short)st[16 * tgl + 8 * gg + j][16 * dt + lc];
        *(bf16x8*)(Vp + (size_t)(tg0 + tgl) * 4096 +
                   (size_t)(dt * 32 + gg * 16 + lc) * 8) = vv;
      }
    }
    __syncthreads();  // out-stage drained before next m overwrites
  }
}

// ---------- Kernel 2: banded attention; parallel epilogue combine ----------
// grid 1024 (XCD-swizzled), block 256 = 4 waves; chunks {2,2,2,2.5} by wave.
__global__ __launch_bounds__(256) void attn_mfma(
    const unsigned short* __restrict__ Qp, const unsigned short* __restrict__ Kp,
    const unsigned short* __restrict__ Vp, float* __restrict__ partial) {
  __shared__ unsigned short plds[4][2][16][40];  // 10.2 KB
  __shared__ float lsh[4][16];
  __shared__ float linv[16];
  __shared__ float fbuf[4][256];  // 4 KB
  const int tid = threadIdx.x;
  const int lane = tid & 63, w = tid >> 6;
  const int bid = blockIdx.x;
  const int blk = (bid & 7) * 128 + (bid >> 3);  // bijective XCD swizzle
  const int b = blk >> 8;
  const int qt = blk & 255;
  const int s0 = qt << 4;
  const int l15 = lane & 15, g = lane >> 4;
  bf16x8 qf[8];
  const unsigned short* qp_ = Qp + ((size_t)b * 256 + qt) * 4096 + (size_t)lane * 8;
#pragma unroll
  for (int kk = 0; kk < 8; ++kk) qf[kk] = *(const bf16x8*)(qp_ + kk * 512);
  const unsigned short* Kb = Kp + (size_t)b * 1048576;
  const unsigned short* Vb = Vp + (size_t)b * 1048576;
  f32x4 acc[16];
  const f32x4 zero = {0.f, 0.f, 0.f, 0.f};
#pragma unroll
  for (int i = 0; i < 16; ++i) acc[i] = zero;
  float lacc[4] = {0.f, 0.f, 0.f, 0.f};
  const int cb = 2 * w;
  const int ce = (w == 3) ? 9 : 2 * w + 2;  // {2,2,2,2.5} (c=8 is half work)
  for (int c = cb; c < ce; ++c) {
    const int t0 = s0 - WIN + c * 32;
    if (t0 + 32 <= 0 || t0 >= SDIM) continue;  // wave-uniform skip
    const int tg = t0 >> 4;
    const int tga = min(max(tg, 0), 255);
    const unsigned short* kap = Kb + (size_t)tga * 4096 + (size_t)lane * 8;
    f32x4 sA = zero, sB = zero;
    const bool full = (c != 8);  // c==8: second 16-t tile fully band-masked
    if (full) {
      const int tgb = min(max(tg + 1, 0), 255);
      const unsigned short* kbp = Kb + (size_t)tgb * 4096 + (size_t)lane * 8;
#pragma unroll
      for (int kk = 0; kk < 8; ++kk) {
        sA = MFMA16(qf[kk], *(const bf16x8*)(kap + kk * 512), sA);
        sB = MFMA16(qf[kk], *(const bf16x8*)(kbp + kk * 512), sB);
      }
    } else {
#pragma unroll
      for (int kk = 0; kk < 8; ++kk)
        sA = MFMA16(qf[kk], *(const bf16x8*)(kap + kk * 512), sA);
    }
    float p0[4], p1[4];
#pragma unroll
    for (int r = 0; r < 4; ++r) {
      int s = s0 + 4 * g + r;
      int ta = t0 + l15, tb = t0 + 16 + l15;
      bool okA = (ta >= 0) && (ta < SDIM) && (ta - s <= WIN) && (ta - s >= -WIN);
      bool okB = full && (tb >= 0) && (tb < SDIM) && (tb - s <= WIN) && (tb - s >= -WIN);
      p0[r] = okA ? __expf(sA[r] * QSCALE) : 0.f;
      p1[r] = okB ? __expf(sB[r] * QSCALE) : 0.f;
    }
#pragma unroll
    for (int r = 0; r < 4; ++r) {
      float v = p0[r] + p1[r];
      v += __shfl_xor(v, 1);
      v += __shfl_xor(v, 2);
      v += __shfl_xor(v, 4);
      v += __shfl_xor(v, 8);
      lacc[r] += v;
    }
    const int bsel = c & 1;
#pragma unroll
    for (int r = 0; r < 4; ++r) {
      plds[w][bsel][4 * g + r][l15] = f2bf(p0[r]);
      plds[w][bsel][4 * g + r][16 + l15] = f2bf(p1[r]);
    }
    bf16x8 pa = *(const bf16x8*)&plds[w][bsel][l15][8 * g];
    const int tgv = min(max(tg + (g >> 1), 0), 255);
    const unsigned short* vp_ =
        Vb + (size_t)tgv * 4096 + (size_t)(g & 1) * 128 + (size_t)l15 * 8;
#pragma unroll
    for (int dt = 0; dt < 16; ++dt)
      acc[dt] = MFMA16(pa, *(const bf16x8*)(vp_ + dt * 256), acc[dt]);
  }
  // ---- parallel epilogue: l-combine -> linv -> weighted row-sum -> fbuf ----
  if (l15 == 0) {
#pragma unroll
    for (int r = 0; r < 4; ++r) lsh[w][4 * g + r] = lacc[r];
  }
  __syncthreads();
  if (tid < 16)
    linv[tid] = 1.0f / (lsh[0][tid] + lsh[1][tid] + lsh[2][tid] + lsh[3][tid]);
  __syncthreads();
  float li[4];
#pragma unroll
  for (int r = 0; r < 4; ++r) li[r] = linv[4 * g + r];
#pragma unroll
  for (int dt = 0; dt < 16; ++dt) {
    float s = acc[dt][0] * li[0] + acc[dt][1] * li[1] + acc[dt][2] * li[2] +
              acc[dt][3] * li[3];
    s += __shfl_xor(s, 16);
    s += __shfl_xor(s, 32);
    if (lane < 16) fbuf[w][dt * 16 + lane] = s;
  }
  __syncthreads();
  partial[(size_t)blk * HDIM + tid] =
      fbuf[0][tid] + fbuf[1][tid] + fbuf[2][tid] + fbuf[3][tid];
}

// ---------- Kernel 3: deterministic mean over S (64 blocks) ----------
__global__ __launch_bounds__(256) void reduce_partials(
    const float* __restrict__ partial, float* __restrict__ out) {
  __shared__ float red[16][17];
  const int cx = blockIdx.x, b = blockIdx.y;
  const int lc = threadIdx.x & 15, rg = threadIdx.x >> 4;
  float s = 0.f;
#pragma unroll
  for (int i = 0; i < 16; ++i)
    s += partial[((size_t)b * 256 + rg * 16 + i) * HDIM + cx * 16 + lc];
  red[rg][lc] = s;
  __syncthreads();
  if (rg == 0) {
    float t = 0.f;
#pragma unroll
    for (int r = 0; r < 16; ++r) t += red[r][lc];
    out[(size_t)b * HDIM + cx * 16 + lc] = t * (1.0f / (float)SDIM);
  }
}

extern "C" void kernel_launch(void* const* d_in, const int* in_sizes, int n_in,
                              void* d_out, int out_size, void* d_ws, size_t ws_size,
                              hipStream_t stream) {
  const float* x  = (const float*)d_in[0];
  const float* Wq = (const float*)d_in[1];
  const float* bq = (const float*)d_in[2];
  const float* Wk = (const float*)d_in[3];
  const float* bk = (const float*)d_in[4];
  const float* Wv = (const float*)d_in[5];
  const float* bv = (const float*)d_in[6];
  float* out = (float*)d_out;

  unsigned short* Wp = (unsigned short*)d_ws;           // 384 KB
  unsigned short* Qp = Wp + 3 * 65536;                  // 8.4 MB
  unsigned short* Kp = Qp + (size_t)NROW * HDIM;        // 8.4 MB
  unsigned short* Vp = Kp + (size_t)NROW * HDIM;        // 8.4 MB
  float* partial = (float*)(Vp + (size_t)NROW * HDIM);  // 1 MB

  dim3 wg(16, 3);
  wconv<<<wg, 256, 0, stream>>>(Wq, Wk, Wv, Wp);
  qkv_mfma<<<512, 256, 0, stream>>>(x, Wp, bq, bk, bv, Qp, Kp, Vp);
  attn_mfma<<<1024, 256, 0, stream>>>(Qp, Kp, Vp, partial);
  dim3 rg(16, 4);
  reduce_partials<<<rg, 256, 0, stream>>>(partial, out);
}